// Round 7
// baseline (187.386 us; speedup 1.0000x reference)
//
#include <hip/hip_runtime.h>
#include <stdint.h>
#include <math.h>

// Must match numpy's unfused fp32 ops exactly: no FMA contraction in this TU.
#pragma clang fp contract(off)

#define N        8192
#define NCHUNK   128      // N / 64
#define NTILE    64       // 2 chunks per tile
#define PDEPTH   4        // prefetch ring depth (power of 2)
#define MAX_OUT  300

#define LD_ACQ(p)    __hip_atomic_load((p), __ATOMIC_ACQUIRE, __HIP_MEMORY_SCOPE_WORKGROUP)
#define LD_RLX(p)    __hip_atomic_load((p), __ATOMIC_RELAXED, __HIP_MEMORY_SCOPE_WORKGROUP)
#define ST_REL(p,v)  __hip_atomic_store((p),(v), __ATOMIC_RELEASE, __HIP_MEMORY_SCOPE_WORKGROUP)

// ---------------------------------------------------------------------------
// Phase 1: rank + scatter fused. 256 blocks; each block stages all 8192 score
// keys in LDS (32 KB), computes FULL ranks for its 32 boxes (8 j-groups per
// box), and scatters boxes/indices. Comparator: score desc, idx asc (unique
// keys -> ranks are a permutation). LDS-BW-bound (~1 MB LDS reads/CU).
// ---------------------------------------------------------------------------
__global__ void __launch_bounds__(256)
nms_rank_scatter(const float4* __restrict__ rois,
                 const float*  __restrict__ scores,
                 float4* __restrict__ sboxes,
                 int*    __restrict__ sidx) {
    __shared__ uint32_t sk[N];        // 32 KB keys (scores >= 0 -> uint-monotonic)
    __shared__ int part[32][8];
    const int t = threadIdx.x;
    const int b = blockIdx.x;
    {
        const uint4* g4 = (const uint4*)scores;
        uint4* s4 = (uint4*)sk;
        for (int q = t; q < N / 4; q += 256) s4[q] = g4[q];
    }
    __syncthreads();

    const int il = t >> 3, g = t & 7;
    const int i  = b * 32 + il;
    const uint32_t my = sk[i];
    int cnt = 0;
    const uint4* k4 = (const uint4*)sk;
    for (int jj = g * 256; jj < g * 256 + 256; ++jj) {   // 1024 j's per thread
        uint4 v = k4[jj];
        int j0 = jj * 4;
        cnt += (v.x > my) || (v.x == my && (j0 + 0) < i);
        cnt += (v.y > my) || (v.y == my && (j0 + 1) < i);
        cnt += (v.z > my) || (v.z == my && (j0 + 2) < i);
        cnt += (v.w > my) || (v.w == my && (j0 + 3) < i);
    }
    part[il][g] = cnt;
    __syncthreads();

    if (t < 32) {
        int r = 0;
#pragma unroll
        for (int q = 0; q < 8; ++q) r += part[t][q];
        const int i2 = b * 32 + t;
        sboxes[r] = rois[i2];
        sidx[r]   = i2;
    }
}

// ---------------------------------------------------------------------------
// Phase 2: suppression bitmask, transposed layout maskT[colchunk][row].
// Exact f64 compare == fp32 IEEE div vs 0.5: fl32(i/d) > 0.5 <=> 2i > d*(1+2^-24)
// (d*(1+2^-24) exact in f64: 24+25 bits <= 53). Verified bit-exact R4-R6.
// ---------------------------------------------------------------------------
__global__ void __launch_bounds__(64)
nms_mask(const float4* __restrict__ sboxes,
         uint64_t* __restrict__ maskT) {
    // decode linear block -> (bi,bj), bj >= bi  (8256 = 128*129/2 blocks)
    const int L = blockIdx.x;
    int bi = (int)(128.5 - sqrt(16512.25 - 2.0 * (double)L));
    if (bi < 0) bi = 0;
    if (bi > 127) bi = 127;
    while (bi < 127 && (bi + 1) * 128 - ((bi + 1) * bi) / 2 <= L) ++bi;
    while (bi > 0 && bi * 128 - (bi * (bi - 1)) / 2 > L) --bi;
    const int bj = bi + (L - (bi * 128 - (bi * (bi - 1)) / 2));

    const int lane = threadIdx.x;          // 0..63 = column within chunk bj
    const float4 cb = sboxes[bj * 64 + lane];
    const float  ac = (cb.z - cb.x) * (cb.w - cb.y);

    __shared__ float4 rb[64];
    __shared__ float  ra[64];
    {
        float4 tt = sboxes[bi * 64 + lane];
        rb[lane] = tt;
        ra[lane] = (tt.z - tt.x) * (tt.w - tt.y);
    }
    __syncthreads();

    const bool diag = (bi == bj);
    const double C = 1.0 + 0x1p-24;        // exactly representable
    uint64_t myword = 0;
    for (int r = 0; r < 64; ++r) {
        const float4 b  = rb[r];           // LDS broadcast
        const float  ar = ra[r];
        float lx    = fmaxf(b.x, cb.x);
        float ly    = fmaxf(b.y, cb.y);
        float hx    = fminf(b.z, cb.z);
        float hy    = fminf(b.w, cb.w);
        float w     = fmaxf(hx - lx, 0.0f);
        float h     = fmaxf(hy - ly, 0.0f);
        float inter = w * h;
        float denom = (ar + ac) - inter;   // left-to-right like numpy
        double di = (double)inter, dd = (double)denom;
        bool sup = (di + di) > (dd * C);   // exact: fl32(di/dd) > 0.5
        uint64_t word = __ballot(sup);
        if (diag)                          // keep only cols > r (wave-uniform)
            word &= (r == 63) ? 0ull : (~0ull << (r + 1));
        myword = (lane == r) ? word : myword;
    }
    maskT[(size_t)bj * N + bi * 64 + lane] = myword;   // 512B coalesced store
}

// ---------------------------------------------------------------------------
// Phase 3: flag-synchronized pipelined scan — NO __syncthreads in the loop,
// so no vmcnt(0) drain on the critical path. Roles:
//  wave 0  resolver : per-tile greedy chain from LDS; folds kept rows into
//                     cols c0+2..c0+5 (uniform ds_atomic_or); waits only
//                     a_flag[it-3] + c_pf.
//  wave 1  prefetch : up to PDEPTH tiles ahead; per tile: diag word, the
//                     c1 column (rows c0..c1, dwordx4/lane) and 4 fold
//                     columns (same packing) into an LDS ring.
//  waves 2-15 appl. : parity-striped (7 waves even tiles / 7 odd); apply
//                     tile it's kept rows to cols >= 2it+6; last arriver
//                     (acq_rel counter) sets a_flag[it] (release).
// Coverage proof for resolver(it) reading removed[c0,c1] (c0=2it):
//  j<=it-3: appliers cover cols >= 2j+6 <= 2it  (a_flag[it-3] acquired)
//  j=it-2 : resolver folds covered 2it-2..2it+1   (same wave)
//  j=it-1 : folds covered 2it..2it+3              (same wave)
//  j=it   : D (diag) + X (c0 rows @ c1) in-chain.
// ---------------------------------------------------------------------------
__device__ __forceinline__ uint64_t rl64(uint64_t v, int l) {
    uint32_t lo = (uint32_t)__builtin_amdgcn_readlane((int)(uint32_t)v, l);
    uint32_t hi = (uint32_t)__builtin_amdgcn_readlane((int)(uint32_t)(v >> 32), l);
    return ((uint64_t)hi << 32) | lo;
}
// word of packed row j (two rows per lane): lane j>>1, half j&1
__device__ __forceinline__ uint64_t rlsel(uint64_t v0, uint64_t v1, int j) {
    uint64_t a = rl64(v0, j >> 1);
    uint64_t b = rl64(v1, j >> 1);
    return (j & 1) ? b : a;
}

__global__ void __launch_bounds__(1024)
nms_scan(const uint64_t* __restrict__ maskT,
         const int*      __restrict__ sidx,
         int*            __restrict__ out) {
    __shared__ uint64_t removed[NCHUNK];           // 1 KB
    __shared__ uint64_t pfD0[PDEPTH][64];          // 2 KB  diag c0, row l at lane l
    __shared__ uint64_t pfXD[PDEPTH][64][2];       // 4 KB  col c1, rows c0..c1 packed
    __shared__ uint64_t pfC[PDEPTH][4][64][2];     // 16 KB fold cols c0+2..c0+5 packed
    __shared__ uint64_t s_kmask[NCHUNK];           // 1 KB
    __shared__ int      s_kbase[NCHUNK];
    __shared__ int      s_klist[PDEPTH][128];
    __shared__ int      s_kcnt[PDEPTH];
    __shared__ int      a_cnt[8];
    __shared__ int      a_flag[NTILE];
    __shared__ int      c_pf, c_res, s_done, s_kept, s_nch;

    const int t    = threadIdx.x;
    const int lane = t & 63;
    const int wave = t >> 6;

    if (t < NCHUNK) removed[t] = 0;
    if (t < NTILE)  a_flag[t] = 0;
    if (t < 8)      a_cnt[t] = 0;
    if (t == 0) { c_pf = 0; c_res = 0; s_done = 0; s_kept = 0; s_nch = 0; }
    __syncthreads();

    if (wave == 1) {
        // ---------------- prefetcher ----------------
        for (int pt = 0; pt < NTILE; ++pt) {
            if (pt >= PDEPTH) {
                bool quit = false;
                for (;;) {
                    if (LD_RLX(&c_res) >= pt - (PDEPTH - 1)) break;
                    if (LD_RLX(&s_done)) { quit = true; break; }
                    __builtin_amdgcn_s_sleep(1);
                }
                if (quit) break;
            }
            const int c0 = 2 * pt, c1 = c0 + 1, sl = pt & (PDEPTH - 1);
            uint64_t d0 = maskT[(size_t)c0 * N + c0 * 64 + lane];
            const uint64_t* xp = &maskT[(size_t)c1 * N + c0 * 64 + 2 * lane];
            uint64_t x0 = xp[0], x1 = xp[1];
            uint64_t cm[4][2];
#pragma unroll
            for (int m = 0; m < 4; ++m) {
                int col = c0 + 2 + m;
                if (col < NCHUNK) {
                    const uint64_t* cp = &maskT[(size_t)col * N + c0 * 64 + 2 * lane];
                    cm[m][0] = cp[0]; cm[m][1] = cp[1];
                } else { cm[m][0] = 0; cm[m][1] = 0; }
            }
            pfD0[sl][lane]    = d0;
            pfXD[sl][lane][0] = x0;  pfXD[sl][lane][1] = x1;
#pragma unroll
            for (int m = 0; m < 4; ++m) {
                pfC[sl][m][lane][0] = cm[m][0];
                pfC[sl][m][lane][1] = cm[m][1];
            }
            if (lane == 0) ST_REL(&c_pf, pt + 1);
        }
    } else if (wave == 0) {
        // ---------------- resolver ----------------
        int kept = 0;
        for (int it = 0; it < NTILE; ++it) {
            const int c0 = 2 * it, c1 = c0 + 1, sl = it & (PDEPTH - 1);
            if (it >= 3) { while (!LD_ACQ(&a_flag[it - 3])) __builtin_amdgcn_s_sleep(1); }
            while (LD_ACQ(&c_pf) <= it) __builtin_amdgcn_s_sleep(1);

            uint64_t D0  = pfD0[sl][lane];
            uint64_t X0  = pfXD[sl][lane][0], X1 = pfXD[sl][lane][1];
            uint64_t C0a = pfC[sl][0][lane][0], C0b = pfC[sl][0][lane][1];
            uint64_t C1a = pfC[sl][1][lane][0], C1b = pfC[sl][1][lane][1];
            uint64_t C2a = pfC[sl][2][lane][0], C2b = pfC[sl][2][lane][1];
            uint64_t C3a = pfC[sl][3][lane][0], C3b = pfC[sl][3][lane][1];
            uint64_t rem0 = removed[c0], rem1 = removed[c1];

            uint64_t keep0 = 0, keep1 = 0, xw = 0, y0 = 0, y1 = 0, y2 = 0, y3 = 0;
            uint64_t cand = ~rem0;                       // chunk c0 chain
            while (cand) {
                int l = __builtin_ctzll(cand);
                keep0 |= (1ull << l);
                uint64_t d = rl64(D0, l);
                xw |= rlsel(X0, X1, l);
                y0 |= rlsel(C0a, C0b, l);  y1 |= rlsel(C1a, C1b, l);
                y2 |= rlsel(C2a, C2b, l);  y3 |= rlsel(C3a, C3b, l);
                cand &= ~d;  cand &= ~(1ull << l);
            }
            rem1 |= xw;
            cand = ~rem1;                                // chunk c1 chain
            while (cand) {
                int q = __builtin_ctzll(cand);
                int j = 64 + q;
                keep1 |= (1ull << q);
                uint64_t d = rlsel(X0, X1, j);           // D1 word (packed in XD)
                y0 |= rlsel(C0a, C0b, j);  y1 |= rlsel(C1a, C1b, j);
                y2 |= rlsel(C2a, C2b, j);  y3 |= rlsel(C3a, C3b, j);
                cand &= ~d;  cand &= ~(1ull << q);
            }
            if (lane == 0) {                             // folds (y* are uniform)
                if (y0 && c0 + 2 < NCHUNK) atomicOr((unsigned long long*)&removed[c0 + 2], (unsigned long long)y0);
                if (y1 && c0 + 3 < NCHUNK) atomicOr((unsigned long long*)&removed[c0 + 3], (unsigned long long)y1);
                if (y2 && c0 + 4 < NCHUNK) atomicOr((unsigned long long*)&removed[c0 + 4], (unsigned long long)y2);
                if (y3 && c0 + 5 < NCHUNK) atomicOr((unsigned long long*)&removed[c0 + 5], (unsigned long long)y3);
            }
            const int n0 = __popcll(keep0), n1 = __popcll(keep1);
            if ((keep0 >> lane) & 1)
                s_klist[sl][__popcll(keep0 & ((1ull << lane) - 1ull))] = c0 * 64 + lane;
            if ((keep1 >> lane) & 1)
                s_klist[sl][n0 + __popcll(keep1 & ((1ull << lane) - 1ull))] = c1 * 64 + lane;
            const bool last = (kept + n0 + n1 >= MAX_OUT) || (it == NTILE - 1);
            if (lane == 0) {
                s_kmask[c0] = keep0;  s_kmask[c1] = keep1;
                s_kbase[c0] = kept;   s_kbase[c1] = kept + n0;
                s_kcnt[sl]  = n0 + n1;
                s_kept      = kept + n0 + n1;
                s_nch       = c1 + 1;
                if (last) ST_REL(&s_done, 1);
                ST_REL(&c_res, it + 1);
            }
            kept += n0 + n1;
            if (last) break;
        }
    } else {
        // ---------------- appliers (waves 2..15) ----------------
        const int aw  = wave - 2;       // 0..13
        const int par = aw / 7;         // tile parity
        const int g   = aw % 7;         // row-group within parity set
        const int colA = 2 * lane, colB = 2 * lane + 1;
        for (int it = par; it < NTILE; it += 2) {
            bool ready = false;
            for (;;) {
                if (LD_ACQ(&c_res) > it) { ready = true; break; }
                if (LD_RLX(&s_done)) { ready = (LD_ACQ(&c_res) > it); break; }
                __builtin_amdgcn_s_sleep(1);
            }
            if (!ready) break;
            const int sl = it & (PDEPTH - 1);
            const int k  = s_kcnt[sl];
            const int colmin = 2 * it + 6;
            uint64_t vA = 0, vB = 0;
            for (int idx = g; idx < k; idx += 7) {
                int row = s_klist[sl][idx];
                if (colA >= colmin) vA |= maskT[(size_t)colA * N + row];
                if (colB >= colmin) vB |= maskT[(size_t)colB * N + row];
            }
            if (vA) atomicOr((unsigned long long*)&removed[colA], (unsigned long long)vA);
            if (vB) atomicOr((unsigned long long*)&removed[colB], (unsigned long long)vB);
            if (lane == 0) {
                int old = __hip_atomic_fetch_add(&a_cnt[it & 7], 1,
                                                 __ATOMIC_ACQ_REL, __HIP_MEMORY_SCOPE_WORKGROUP);
                if (old == 6) {                           // 7th (last) arriver
                    __hip_atomic_store(&a_cnt[it & 7], 0,
                                       __ATOMIC_RELAXED, __HIP_MEMORY_SCOPE_WORKGROUP);
                    ST_REL(&a_flag[it], 1);
                }
            }
        }
    }

    __syncthreads();

    // ---- parallel output pass ----
    const int nch = s_nch;
    for (int cp = t >> 6; cp < nch; cp += 16) {
        uint64_t km = s_kmask[cp];
        if ((km >> lane) & 1) {
            int pos = s_kbase[cp] + __popcll(km & ((1ull << lane) - 1ull));
            if (pos < MAX_OUT) out[pos] = sidx[cp * 64 + lane];
        }
    }
    const int start = s_kept < MAX_OUT ? s_kept : MAX_OUT;
    for (int p = start + t; p < MAX_OUT; p += 1024) out[p] = -1;
}

// ---------------------------------------------------------------------------
extern "C" void kernel_launch(void* const* d_in, const int* in_sizes, int n_in,
                              void* d_out, int out_size, void* d_ws, size_t ws_size,
                              hipStream_t stream) {
    const float4* rois   = (const float4*)d_in[0];   // [8192,4] fp32
    const float*  scores = (const float*)d_in[1];    // [8192]   fp32
    int* out = (int*)d_out;                          // [300] int32

    // workspace layout (~8.2 MB)
    float4*   sboxes = (float4*)d_ws;                                  // 128 KiB
    int*      sidx   = (int*)((char*)d_ws + 128 * 1024);               //  32 KiB
    uint64_t* maskT  = (uint64_t*)((char*)d_ws + 160 * 1024);          //   8 MiB

    nms_rank_scatter<<<dim3(256), dim3(256), 0, stream>>>(rois, scores, sboxes, sidx);
    nms_mask<<<dim3(8256), dim3(64), 0, stream>>>(sboxes, maskT);
    nms_scan<<<dim3(1), dim3(1024), 0, stream>>>(maskT, sidx, out);
}

// Round 8
// 152.698 us; speedup vs baseline: 1.2272x; 1.2272x over previous
//
#include <hip/hip_runtime.h>
#include <stdint.h>
#include <math.h>

// Must match numpy's unfused fp32 ops exactly: no FMA contraction in this TU.
#pragma clang fp contract(off)

#define N        8192
#define NCHUNK   128      // N / 64
#define TCH      4        // chunks per scan tile (256 boxes)
#define TNT      (NCHUNK / TCH)   // 32 tiles
#define MAX_OUT  300

// ---------------------------------------------------------------------------
// Phase 1: rank + scatter fused (unchanged from R6; ~6 us).
// ---------------------------------------------------------------------------
__global__ void __launch_bounds__(256)
nms_rank_scatter(const float4* __restrict__ rois,
                 const float*  __restrict__ scores,
                 float4* __restrict__ sboxes,
                 int*    __restrict__ sidx) {
    __shared__ uint32_t sk[N];        // 32 KB keys (scores >= 0 -> uint-monotonic)
    __shared__ int part[32][8];
    const int t = threadIdx.x;
    const int b = blockIdx.x;
    {
        const uint4* g4 = (const uint4*)scores;
        uint4* s4 = (uint4*)sk;
        for (int q = t; q < N / 4; q += 256) s4[q] = g4[q];
    }
    __syncthreads();

    const int il = t >> 3, g = t & 7;
    const int i  = b * 32 + il;
    const uint32_t my = sk[i];
    int cnt = 0;
    const uint4* k4 = (const uint4*)sk;
    for (int jj = g * 256; jj < g * 256 + 256; ++jj) {
        uint4 v = k4[jj];
        int j0 = jj * 4;
        cnt += (v.x > my) || (v.x == my && (j0 + 0) < i);
        cnt += (v.y > my) || (v.y == my && (j0 + 1) < i);
        cnt += (v.z > my) || (v.z == my && (j0 + 2) < i);
        cnt += (v.w > my) || (v.w == my && (j0 + 3) < i);
    }
    part[il][g] = cnt;
    __syncthreads();

    if (t < 32) {
        int r = 0;
#pragma unroll
        for (int q = 0; q < 8; ++q) r += part[t][q];
        const int i2 = b * 32 + t;
        sboxes[r] = rois[i2];
        sidx[r]   = i2;
    }
}

// ---------------------------------------------------------------------------
// Phase 2: suppression bitmask, transposed layout maskT[colchunk][row]
// (unchanged from R6). Exact f64 compare == fp32 IEEE div vs 0.5.
// ---------------------------------------------------------------------------
__global__ void __launch_bounds__(64)
nms_mask(const float4* __restrict__ sboxes,
         uint64_t* __restrict__ maskT) {
    const int L = blockIdx.x;
    int bi = (int)(128.5 - sqrt(16512.25 - 2.0 * (double)L));
    if (bi < 0) bi = 0;
    if (bi > 127) bi = 127;
    while (bi < 127 && (bi + 1) * 128 - ((bi + 1) * bi) / 2 <= L) ++bi;
    while (bi > 0 && bi * 128 - (bi * (bi - 1)) / 2 > L) --bi;
    const int bj = bi + (L - (bi * 128 - (bi * (bi - 1)) / 2));

    const int lane = threadIdx.x;
    const float4 cb = sboxes[bj * 64 + lane];
    const float  ac = (cb.z - cb.x) * (cb.w - cb.y);

    __shared__ float4 rb[64];
    __shared__ float  ra[64];
    {
        float4 tt = sboxes[bi * 64 + lane];
        rb[lane] = tt;
        ra[lane] = (tt.z - tt.x) * (tt.w - tt.y);
    }
    __syncthreads();

    const bool diag = (bi == bj);
    const double C = 1.0 + 0x1p-24;
    uint64_t myword = 0;
    for (int r = 0; r < 64; ++r) {
        const float4 b  = rb[r];
        const float  ar = ra[r];
        float lx    = fmaxf(b.x, cb.x);
        float ly    = fmaxf(b.y, cb.y);
        float hx    = fminf(b.z, cb.z);
        float hy    = fminf(b.w, cb.w);
        float w     = fmaxf(hx - lx, 0.0f);
        float h     = fmaxf(hy - ly, 0.0f);
        float inter = w * h;
        float denom = (ar + ac) - inter;
        double di = (double)inter, dd = (double)denom;
        bool sup = (di + di) > (dd * C);
        uint64_t word = __ballot(sup);
        if (diag)
            word &= (r == 63) ? 0ull : (~0ull << (r + 1));
        myword = (lane == r) ? word : myword;
    }
    maskT[(size_t)bj * N + bi * 64 + lane] = myword;
}

// ---------------------------------------------------------------------------
// Phase 3: barrier-synced wide-tile scan. 32 tiles x 4 chunks, ONE
// __syncthreads per tile (8x fewer barrier drains than R5's 256).
//  wave 0    : resolve 4 chunks from LDS swath (in-tile cross via register
//              readlanes) + fold next tile's 4 cols itself.
//  waves 1-3 : prefetch tile t+1 swath (rows [c0',c0'+256) x cols c0'..c0'+7,
//              16 KB coalesced) into LDS dbuf.
//  waves 4-15: apply tile t-1's kept rows to cols >= 4t+4 (one parallel RT).
// Coverage for resolve(t) reading removed[4t..4t+3]:
//  apply(t-2) covered cols >= 4t   (finished interval t-1)
//  fold(t-1)  covered cols 4t..4t+3 (wave 0 itself, interval t-1)
//  in-tile    cross/diag via registers (same interval).
// ---------------------------------------------------------------------------
__device__ __forceinline__ uint64_t rl64(uint64_t v, int l) {
    uint32_t lo = (uint32_t)__builtin_amdgcn_readlane((int)(uint32_t)v, l);
    uint32_t hi = (uint32_t)__builtin_amdgcn_readlane((int)(uint32_t)(v >> 32), l);
    return ((uint64_t)hi << 32) | lo;
}

__global__ void __launch_bounds__(1024)
nms_scan(const uint64_t* __restrict__ maskT,
         const int*      __restrict__ sidx,
         int*            __restrict__ out) {
    __shared__ uint64_t removed[NCHUNK];           // 1 KB
    __shared__ uint64_t pf[2][2 * TCH][64 * TCH];  // 32 KB: [buf][col d 0..7][row r 0..255]
    __shared__ uint64_t s_kmask[NCHUNK];           // 1 KB
    __shared__ int      s_kbase[NCHUNK];
    __shared__ int      s_klist[2][256];           // tile kept rows, by tile parity
    __shared__ int      s_kcnt[2];
    __shared__ int      s_done, s_kept, s_nch;

    const int t    = threadIdx.x;
    const int lane = t & 63;
    const int wave = t >> 6;

    if (t < NCHUNK) removed[t] = 0;
    if (t == 0) { s_done = 0; s_kept = 0; s_nch = 0; s_kcnt[0] = 0; s_kcnt[1] = 0; }
    if (wave >= 1 && wave <= 3) {                  // preload tile 0 swath
        const int tl = t - 64;
        for (int q = tl; q < 2048; q += 192) {
            int d = q >> 8, r = q & 255;           // col 0..7, row 0..255
            pf[0][d][r] = maskT[(size_t)d * N + r];
        }
    }
    __syncthreads();

    for (int tt = 0; tt < TNT; ++tt) {
        const int c0  = TCH * tt;
        const int buf = tt & 1;

        if (wave == 0) {
            // ---------------- resolver ----------------
            uint64_t rem[TCH];
#pragma unroll
            for (int s = 0; s < TCH; ++s) rem[s] = removed[c0 + s];
            uint64_t y0 = 0, y1 = 0, y2 = 0, y3 = 0;   // folds for cols c0+4..c0+7
            uint64_t keepm[TCH];
            int      n[TCH];
#pragma unroll
            for (int s = 0; s < TCH; ++s) {
                uint64_t D  = pf[buf][s][s * 64 + lane];        // own-chunk diag
                uint64_t A4 = pf[buf][4][s * 64 + lane];        // fold cols
                uint64_t A5 = pf[buf][5][s * 64 + lane];
                uint64_t A6 = pf[buf][6][s * 64 + lane];
                uint64_t A7 = pf[buf][7][s * 64 + lane];
                uint64_t X1 = (s + 1 < TCH) ? pf[buf][s + 1][s * 64 + lane] : 0;
                uint64_t X2 = (s + 2 < TCH) ? pf[buf][s + 2][s * 64 + lane] : 0;
                uint64_t X3 = (s + 3 < TCH) ? pf[buf][s + 3][s * 64 + lane] : 0;
                uint64_t cand = ~rem[s];
                uint64_t keep = 0;
                while (cand) {
                    int l = __builtin_ctzll(cand);
                    keep |= (1ull << l);
                    uint64_t d0 = rl64(D, l);
                    cand &= ~d0;
                    cand &= ~(1ull << l);
                    if (s + 1 < TCH) rem[s + 1] |= rl64(X1, l); // in-tile cross
                    if (s + 2 < TCH) rem[s + 2] |= rl64(X2, l);
                    if (s + 3 < TCH) rem[s + 3] |= rl64(X3, l);
                    y0 |= rl64(A4, l);                           // next-tile folds
                    y1 |= rl64(A5, l);
                    y2 |= rl64(A6, l);
                    y3 |= rl64(A7, l);
                }
                keepm[s] = keep;
                n[s] = __popcll(keep);
            }
            if (lane == 0) {                       // fold writes (y uniform)
                if (y0 && c0 + 4 < NCHUNK) atomicOr((unsigned long long*)&removed[c0 + 4], (unsigned long long)y0);
                if (y1 && c0 + 5 < NCHUNK) atomicOr((unsigned long long*)&removed[c0 + 5], (unsigned long long)y1);
                if (y2 && c0 + 6 < NCHUNK) atomicOr((unsigned long long*)&removed[c0 + 6], (unsigned long long)y2);
                if (y3 && c0 + 7 < NCHUNK) atomicOr((unsigned long long*)&removed[c0 + 7], (unsigned long long)y3);
            }
            int barr[TCH];
            barr[0] = 0;
#pragma unroll
            for (int s = 1; s < TCH; ++s) barr[s] = barr[s - 1] + n[s - 1];
#pragma unroll
            for (int s = 0; s < TCH; ++s) {        // tile-local kept list
                uint64_t km = keepm[s];
                if ((km >> lane) & 1) {
                    int p = barr[s] + __popcll(km & ((1ull << lane) - 1ull));
                    s_klist[buf][p] = (c0 + s) * 64 + lane;
                }
            }
            if (lane == 0) {
                const int kprev = s_kept;
                const int ktile = barr[TCH - 1] + n[TCH - 1];
#pragma unroll
                for (int s = 0; s < TCH; ++s) {
                    s_kmask[c0 + s] = keepm[s];
                    s_kbase[c0 + s] = kprev + barr[s];
                }
                s_kcnt[buf] = ktile;
                s_kept      = kprev + ktile;
                s_nch       = c0 + TCH;
                if (kprev + ktile >= MAX_OUT || tt == TNT - 1) s_done = 1;
            }
        } else if (wave <= 3) {
            // ---------------- prefetch tile tt+1 ----------------
            const int tp = tt + 1;
            if (tp < TNT) {
                const int c0p = TCH * tp;
                const int tl  = t - 64;
                for (int q = tl; q < 2048; q += 192) {
                    int d = q >> 8, r = q & 255;
                    int col = c0p + d;
                    if (col < NCHUNK)
                        pf[buf ^ 1][d][r] = maskT[(size_t)col * N + (size_t)c0p * 64 + r];
                }
            }
        } else {
            // ---------------- apply tile tt-1 (waves 4..15) ----------------
            if (tt >= 1) {
                const int g      = wave - 4;            // 0..11 row-stripe
                const int sl     = buf ^ 1;             // (tt-1) & 1
                const int k      = s_kcnt[sl];
                const int colmin = TCH * tt + TCH;      // 4tt+4
                const int colA   = 2 * lane, colB = 2 * lane + 1;
                uint64_t vA = 0, vB = 0;
                for (int idx = g; idx < k; idx += 12) {
                    int row = s_klist[sl][idx];
                    if (colA >= colmin) vA |= maskT[(size_t)colA * N + row];
                    if (colB >= colmin) vB |= maskT[(size_t)colB * N + row];
                }
                if (vA) atomicOr((unsigned long long*)&removed[colA], (unsigned long long)vA);
                if (vB) atomicOr((unsigned long long*)&removed[colB], (unsigned long long)vB);
            }
        }
        __syncthreads();
        if (s_done) break;
    }

    // ---- parallel output pass ----
    const int nch = s_nch;
    for (int cp = t >> 6; cp < nch; cp += 16) {
        uint64_t km = s_kmask[cp];
        if ((km >> lane) & 1) {
            int pos = s_kbase[cp] + __popcll(km & ((1ull << lane) - 1ull));
            if (pos < MAX_OUT) out[pos] = sidx[cp * 64 + lane];
        }
    }
    const int start = s_kept < MAX_OUT ? s_kept : MAX_OUT;
    for (int p = start + t; p < MAX_OUT; p += 1024) out[p] = -1;
}

// ---------------------------------------------------------------------------
extern "C" void kernel_launch(void* const* d_in, const int* in_sizes, int n_in,
                              void* d_out, int out_size, void* d_ws, size_t ws_size,
                              hipStream_t stream) {
    const float4* rois   = (const float4*)d_in[0];   // [8192,4] fp32
    const float*  scores = (const float*)d_in[1];    // [8192]   fp32
    int* out = (int*)d_out;                          // [300] int32

    // workspace layout (~8.2 MB)
    float4*   sboxes = (float4*)d_ws;                                  // 128 KiB
    int*      sidx   = (int*)((char*)d_ws + 128 * 1024);               //  32 KiB
    uint64_t* maskT  = (uint64_t*)((char*)d_ws + 160 * 1024);          //   8 MiB

    nms_rank_scatter<<<dim3(256), dim3(256), 0, stream>>>(rois, scores, sboxes, sidx);
    nms_mask<<<dim3(8256), dim3(64), 0, stream>>>(sboxes, maskT);
    nms_scan<<<dim3(1), dim3(1024), 0, stream>>>(maskT, sidx, out);
}